// Round 21
// baseline (681.629 us; speedup 1.0000x reference)
//
#include <hip/hip_runtime.h>
#include <math.h>

#define NB 32
#define NP 24656
#define NO 16
#define NC 81
#define ND 85   // 4 + NC
#define THRESH_F 0.5f
#define NEGPOS_I 3
#define VAR0_F 0.1f
#define VAR1_F 0.2f
#define NEG_HUGE -1e30f

#define BPCNT (NB * NP)
#define MBLK2 25         // k_match blocks per batch row = ceil(NP/1024)
#define CHB32 771        // 32-row chunks per batch row = ceil(NP/32)
#define SPB2 56          // k_main blocks per batch row (56*32 = 1792 = 7/CU)
#define CB32 11264       // staged bytes per chunk = 11 x 1024 (>= 32*85*4)

typedef unsigned long long u64;

// ---------------------------------------------------------------- match body
__device__ __forceinline__ void match_body(
    const float* __restrict__ tb, const float* __restrict__ priors,
    u64* __restrict__ mcand, int b, int bx, int tid,
    u64 (*kbuf)[256], u64 (*pbuf)[16]) {
    const int p0 = bx * 1024 + tid * 4;
    float pl[4], pt[4], prr[4], pbm[4], pa[4];
    bool pv[4];
#pragma unroll
    for (int j = 0; j < 4; ++j) {
        const int p = p0 + j;
        pv[j] = (p < NP);
        const float4 q = pv[j] ? ((const float4*)priors)[p]
                               : make_float4(0.f, 0.f, 1.f, 1.f);
        pl[j] = q.x - q.z * 0.5f; pt[j] = q.y - q.w * 0.5f;
        prr[j] = q.x + q.z * 0.5f; pbm[j] = q.y + q.w * 0.5f;
        pa[j] = (prr[j] - pl[j]) * (pbm[j] - pt[j]);
    }
    for (int o = 0; o < NO; ++o) {
        const float al = tb[o * 4], at = tb[o * 4 + 1];
        const float ar = tb[o * 4 + 2], ab = tb[o * 4 + 3];
        const float aarea = (ar - al) * (ab - at);
        u64 kmax = 0ull;
#pragma unroll
        for (int j = 0; j < 4; ++j) {
            float iw = fminf(ar, prr[j]) - fmaxf(al, pl[j]); iw = fmaxf(iw, 0.f);
            float ih = fminf(ab, pbm[j]) - fmaxf(at, pt[j]); ih = fmaxf(ih, 0.f);
            const float inter = iw * ih;
            const float iou = inter / (aarea + pa[j] - inter);
            if (pv[j]) {
                const u64 key = ((u64)__float_as_uint(iou) << 32) |
                                (u64)(0xFFFFFFFFu - (unsigned)(p0 + j));
                kmax = (key > kmax) ? key : kmax;
            }
        }
        kbuf[o][tid] = kmax;
    }
    __syncthreads();
    {
        const int o = tid >> 4, seg = tid & 15;
        u64 m = kbuf[o][seg];
#pragma unroll
        for (int i = 1; i < 16; ++i) {
            const u64 v = kbuf[o][i * 16 + seg];
            m = (v > m) ? v : m;
        }
        pbuf[o][seg] = m;
    }
    __syncthreads();
    if (tid < NO) {
        u64 m = pbuf[tid][0];
#pragma unroll
        for (int i = 1; i < 16; ++i) {
            const u64 v = pbuf[tid][i];
            m = (v > m) ? v : m;
        }
        mcand[((size_t)(b * NO + tid)) * MBLK2 + bx] = m;
    }
}

// ---------------------------------------------------------------- match
__global__ __launch_bounds__(256) void k_match(
    const float* __restrict__ tboxes, const float* __restrict__ priors,
    u64* __restrict__ mcand,
    int* __restrict__ npos, float* __restrict__ accB, int* __restrict__ done) {
    const int b = blockIdx.y, bx = blockIdx.x, tid = threadIdx.x;
    __shared__ float tb[NO * 4];
    __shared__ u64 kbuf[NO][256];
    __shared__ u64 pbuf[NO][16];
    if (bx == 0 && b == 0) {
        if (tid < NB) npos[tid] = 0;
        if (tid < 2 * NB) accB[tid] = 0.f;
        if (tid == 0) *done = 0;
    }
    if (tid < NO * 4) tb[tid] = tboxes[b * NO * 4 + tid];
    __syncthreads();
    match_body(tb, priors, mcand, b, bx, tid, kbuf, pbuf);
}

// ---------------------------------------------------------------- match PROBE
// DIAGNOSTIC x24 into dummy mcand2: m = dur/24.
__global__ __launch_bounds__(256) void k_match_probe(
    const float* __restrict__ tboxes, const float* __restrict__ priors,
    u64* __restrict__ mcand2) {
    const int b = blockIdx.y, bx = blockIdx.x, tid = threadIdx.x;
    __shared__ float tb[NO * 4];
    __shared__ u64 kbuf[NO][256];
    __shared__ u64 pbuf[NO][16];
    if (tid < NO * 4) tb[tid] = tboxes[b * NO * 4 + tid];
    __syncthreads();
    for (int rep = 0; rep < 24; ++rep) {
        match_body(tb, priors, mcand2, b, bx, tid, kbuf, pbuf);
        __syncthreads();
    }
}

// ---------------------------------------------------------------- stage (reg)
__device__ __forceinline__ void stage_load(float4* vreg,
                                           const char* __restrict__ gpred,
                                           int b, int r0, int lane) {
    const size_t off = ((size_t)b * NP + r0) * 340ull;
    const char* g = gpred + off;
    const bool unsafe = (b == NB - 1) && (r0 + 34 > NP);
    if (!unsafe) {
#pragma unroll
        for (int k = 0; k < 11; ++k)
            vreg[k] = *(const float4*)(g + k * 1024 + lane * 16);
    } else {
        const int nf4 = (NP - r0) * ND / 4;
        const float4* gs = (const float4*)g;
#pragma unroll
        for (int k = 0; k < 11; ++k) {
            const int idx = k * 64 + lane;
            vreg[k] = (idx < nf4) ? gs[idx]
                                  : make_float4(0.f, 0.f, 0.f, 0.f);
        }
    }
}

__device__ __forceinline__ void stage_write(char* buf, const float4* vreg,
                                            int lane) {
#pragma unroll
    for (int k = 0; k < 11; ++k)
        *(float4*)(buf + k * 1024 + lane * 16) = vreg[k];
}

// ---------------------------------------------------------------- main fused
__global__ __launch_bounds__(64) void k_main(
    const float* __restrict__ pred, const float* __restrict__ tboxes,
    const int* __restrict__ tlabels, const float* __restrict__ priors,
    const u64* __restrict__ mcand,
    float* __restrict__ lr, int* __restrict__ npos, float* __restrict__ accB) {
    __shared__ char smem[2][CB32];
    __shared__ float tbs[NO * 4];

    const int b = blockIdx.y;
    const int span = blockIdx.x;
    const int lane = threadIdx.x;
    const size_t bbase = (size_t)b * NP;
    const char* gpred = (const char*)pred;

    char* cur = smem[0];
    char* nxt = smem[1];

    const int rho = lane >> 1;
    const int h = lane & 1;
    const int c0 = rho & 3;
    const int Ab = 16 * (21 * rho + (rho >> 2));
    const int sbase = h ? 11 : 1;

    tbs[lane] = tboxes[b * NO * 4 + lane];

    u64 pbk = 0ull;
    if (lane < NO) {
        const u64* c = mcand + (size_t)(b * NO + lane) * MBLK2;
        for (int i = 0; i < MBLK2; ++i) {
            const u64 v = c[i];
            pbk = (v > pbk) ? v : pbk;
        }
    }
    int p16[NO];
#pragma unroll
    for (int j = 0; j < NO; ++j) {
        const u64 kj = __shfl(pbk, j, 64);
        p16[j] = (int)(0xFFFFFFFFu - (unsigned)(kj & 0xFFFFFFFFull));
    }

    float my_ll = 0.f, my_ce = 0.f;
    int my_np = 0;

    int chunk = span;
    int next_chunk = chunk + SPB2;
    {
        float4 vreg[11];
        stage_load(vreg, gpred, b, chunk * 32, lane);
        stage_write(cur, vreg, lane);
    }

    while (chunk < CHB32) {
        float4 vreg[11];
        const bool have_next = (next_chunk < CHB32);
        if (have_next)
            stage_load(vreg, gpred, b, next_chunk * 32, lane);

        const int r0 = chunk * 32;
        const int nrows = min(32, NP - r0);
        const int p = r0 + rho;
        const bool rok = (rho < nrows);

        float4 v[11];
#pragma unroll
        for (int k = 0; k < 11; ++k)
            v[k] = *(const float4*)(cur + Ab + 16 * (sbase + k));

        float vals[44];
#pragma unroll
        for (int k = 0; k < 11; ++k) {
            const float xs[4] = {v[k].x, v[k].y, v[k].z, v[k].w};
#pragma unroll
            for (int t = 0; t < 4; ++t) {
                bool ok;
                if (k == 0)
                    ok = h ? false : (t >= c0);
                else if (k == 10)
                    ok = h ? (t <= c0) : true;
                else
                    ok = true;
                vals[4 * k + t] = ok ? xs[t] : NEG_HUGE;
            }
        }
        float mA = vals[0], mB = vals[1];
#pragma unroll
        for (int j = 2; j < 44; j += 2) {
            mA = fmaxf(mA, vals[j]);
            mB = fmaxf(mB, vals[j + 1]);
        }
        float m = fmaxf(mA, mB);
        m = fmaxf(m, __shfl_xor(m, 1, 64));

        float sA = 0.f, sB = 0.f;
#pragma unroll
        for (int j = 0; j < 44; j += 2) {
            sA += __expf(vals[j] - m);
            sB += __expf(vals[j + 1] - m);
        }
        float ssum = sA + sB;
        ssum += __shfl_xor(ssum, 1, 64);
        const float lse = m + __logf(ssum);

        float bv = -1.f;
        int bi = 0;
        {
            const float4 pq = rok ? *((const float4*)priors + p)
                                  : make_float4(0.f, 0.f, 1.f, 1.f);
            const float prl = pq.x - pq.z * 0.5f, prt = pq.y - pq.w * 0.5f;
            const float prr2 = pq.x + pq.z * 0.5f, prb = pq.y + pq.w * 0.5f;
            const float parea = (prr2 - prl) * (prb - prt);
            const int obase = h * 8;
#pragma unroll
            for (int oj = 0; oj < 8; ++oj) {
                const int o = obase + oj;
                const float al = tbs[o * 4 + 0], at = tbs[o * 4 + 1];
                const float ar = tbs[o * 4 + 2], ab = tbs[o * 4 + 3];
                float iw = fminf(ar, prr2) - fmaxf(al, prl); iw = fmaxf(iw, 0.f);
                float ih = fminf(ab, prb) - fmaxf(at, prt); ih = fmaxf(ih, 0.f);
                const float inter = iw * ih;
                const float aarea = (ar - al) * (ab - at);
                const float iou = inter / (aarea + parea - inter);
                if (iou > bv) { bv = iou; bi = o; }
            }
            const float ov = __shfl_xor(bv, 1, 64);
            const int oi = __shfl_xor(bi, 1, 64);
            if (ov > bv || (ov == bv && oi < bi)) { bv = ov; bi = oi; }
        }

        if (h == 0 && rok) {
            const float bg = (c0 == 0) ? v[0].x : (c0 == 1) ? v[0].y
                           : (c0 == 2) ? v[0].z : v[0].w;
            int o_f = -1;
#pragma unroll
            for (int j = 0; j < NO; ++j)
                if (p == p16[j]) o_f = j;
            const bool forced = (o_f >= 0);
            const bool pos = forced || (bv >= THRESH_F);
            const int o = forced ? o_f : bi;
            lr[bbase + p] = pos ? 0.f : (lse - bg);
            if (pos) {
                my_np += 1;
                const float* rowp = (const float*)(cur + 340 * rho);
                const int lbl = tlabels[b * NO + o] + 1;
                my_ce += lse - rowp[4 + lbl];
                const float4 pq = *((const float4*)priors + p);
                const float tx0 = tbs[o * 4 + 0];
                const float ty0 = tbs[o * 4 + 1];
                const float tx1 = tbs[o * 4 + 2];
                const float ty1 = tbs[o * 4 + 3];
                const float g0 = ((tx0 + tx1) * 0.5f - pq.x) / (VAR0_F * pq.z);
                const float g1 = ((ty0 + ty1) * 0.5f - pq.y) / (VAR0_F * pq.w);
                const float g2 = __logf((tx1 - tx0) / pq.z) / VAR1_F;
                const float g3 = __logf((ty1 - ty0) / pq.w) / VAR1_F;
                float dd, ad;
                dd = rowp[0] - g0; ad = fabsf(dd); my_ll += (ad < 1.f) ? 0.5f * dd * dd : (ad - 0.5f);
                dd = rowp[1] - g1; ad = fabsf(dd); my_ll += (ad < 1.f) ? 0.5f * dd * dd : (ad - 0.5f);
                dd = rowp[2] - g2; ad = fabsf(dd); my_ll += (ad < 1.f) ? 0.5f * dd * dd : (ad - 0.5f);
                dd = rowp[3] - g3; ad = fabsf(dd); my_ll += (ad < 1.f) ? 0.5f * dd * dd : (ad - 0.5f);
            }
        }

        if (have_next)
            stage_write(nxt, vreg, lane);

        chunk = next_chunk;
        next_chunk += SPB2;
        char* tmp = cur; cur = nxt; nxt = tmp;
    }

    for (int d2 = 1; d2 < 64; d2 <<= 1) {
        my_ll += __shfl_xor(my_ll, d2, 64);
        my_ce += __shfl_xor(my_ce, d2, 64);
        my_np += __shfl_xor(my_np, d2, 64);
    }
    if (lane == 0) {
        if (my_ll != 0.f) atomicAdd(&accB[b * 2 + 0], my_ll);
        if (my_ce != 0.f) atomicAdd(&accB[b * 2 + 1], my_ce);
        if (my_np) atomicAdd(&npos[b], my_np);
    }
}

// ---------------------------------------------------------------- select body
__device__ __forceinline__ float select_body(
    const float4* __restrict__ cch, const bool* __restrict__ cvz, int K0,
    int tid, int lane, int wid, int sub, unsigned (*hist16)[16],
    unsigned* chist, int* sh_bucket, int* sh_knew, float* wsum, int* wcnt) {
    int k = K0;
    unsigned prefix = 0;
    const int shifts[3] = {21, 10, 0};
    const unsigned masks[3] = {0u, 0xFFE00000u, 0xFFFFFC00u};

    for (int pass = 0; pass < 3; ++pass) {
        const int shift = shifts[pass];
        const unsigned mask_hi = masks[pass];
        {
            uint4* hz = (uint4*)hist16;
            for (int j = tid; j < 2048 * 4; j += 1024)
                hz[j] = make_uint4(0u, 0u, 0u, 0u);
        }
        __syncthreads();
#pragma unroll
        for (int j = 0; j < 7; ++j) {
            if (cvz[j]) {
                const float4 v4 = cch[j];
#pragma unroll
                for (int c = 0; c < 4; ++c) {
                    const float f = (c == 0) ? v4.x : (c == 1) ? v4.y
                                  : (c == 2) ? v4.z : v4.w;
                    const unsigned v = __float_as_uint(f);
                    if ((v & mask_hi) == (prefix & mask_hi))
                        atomicAdd(&hist16[(v >> shift) & 2047u][sub], 1u);
                }
            }
        }
        __syncthreads();
        for (int j = tid; j < 2048; j += 1024) {
            const uint4* hp = (const uint4*)&hist16[j][0];
            const uint4 a = hp[0], b4 = hp[1], c4 = hp[2], d4 = hp[3];
            chist[j] = a.x + a.y + a.z + a.w + b4.x + b4.y + b4.z + b4.w +
                       c4.x + c4.y + c4.z + c4.w + d4.x + d4.y + d4.z + d4.w;
        }
        __syncthreads();
        if (tid < 64) {
            unsigned g = 0;
            for (int j = 0; j < 32; ++j) g += chist[lane * 32 + j];
            unsigned T = g;
            for (int d = 1; d < 64; d <<= 1) {
                const unsigned t = __shfl_down(T, d, 64);
                if (lane + d < 64) T += t;
            }
            const unsigned E = T - g;
            const bool hit = (E < (unsigned)k) && ((unsigned)k <= T);
            const unsigned long long msk = __ballot(hit);
            const int wl = __ffsll(msk) - 1;
            if (lane == wl) {
                unsigned cum = E;
                int bsel = lane * 32, kn = k;
                for (int j = 31; j >= 0; --j) {
                    const unsigned c = chist[lane * 32 + j];
                    if (cum + c >= (unsigned)k) {
                        bsel = lane * 32 + j;
                        kn = k - (int)cum;
                        break;
                    }
                    cum += c;
                }
                *sh_bucket = bsel;
                *sh_knew = kn;
            }
        }
        __syncthreads();
        prefix |= ((unsigned)(*sh_bucket)) << shift;
        k = *sh_knew;
        __syncthreads();
    }
    const float T = __uint_as_float(prefix);

    float msum = 0.f;
    int mcnt = 0;
#pragma unroll
    for (int j = 0; j < 7; ++j) {
        if (cvz[j]) {
            const float4 v4 = cch[j];
#pragma unroll
            for (int c = 0; c < 4; ++c) {
                const float f = (c == 0) ? v4.x : (c == 1) ? v4.y
                              : (c == 2) ? v4.z : v4.w;
                if (__float_as_uint(f) > prefix) { msum += f; mcnt++; }
            }
        }
    }
    for (int s = 32; s > 0; s >>= 1) {
        msum += __shfl_down(msum, s, 64);
        mcnt += __shfl_down(mcnt, s, 64);
    }
    if (lane == 0) { wsum[wid] = msum; wcnt[wid] = mcnt; }
    __syncthreads();
    float negsum = 0.f;
    if (tid == 0) {
        float tot = 0.f;
        int cnt = 0;
        for (int w = 0; w < 16; ++w) { tot += wsum[w]; cnt += wcnt[w]; }
        negsum = tot + (float)(K0 - cnt) * T;
    }
    __syncthreads();
    return negsum;
}

// ---------------------------------------------------------------- select
__global__ __launch_bounds__(1024) void k_select(
    const float* __restrict__ lrk, const int* __restrict__ npos,
    float* __restrict__ accB, int* __restrict__ done, float* __restrict__ out) {
    const int b = blockIdx.x;
    const float4* row4 = (const float4*)(lrk + (size_t)b * NP);
    const int tid = threadIdx.x;
    const int lane = tid & 63;
    const int wid = tid >> 6;
    const int sub = lane & 15;

    __shared__ unsigned hist16[2048][16];
    __shared__ unsigned chist[2048];
    __shared__ int sh_bucket, sh_knew;
    __shared__ float wsum[16];
    __shared__ int wcnt[16];

    float4 cch[7];
    bool cvz[7];
#pragma unroll
    for (int j = 0; j < 7; ++j) {
        const int i = tid + j * 1024;
        cvz[j] = (i < NP / 4);
        cch[j] = cvz[j] ? row4[i] : make_float4(0.f, 0.f, 0.f, 0.f);
    }

    const int K0 = min(npos[b] * NEGPOS_I, NP);
    const float negsum = select_body(cch, cvz, K0, tid, lane, wid, sub, hist16,
                                     chist, &sh_bucket, &sh_knew, wsum, wcnt);
    if (tid == 0) {
        atomicAdd(&accB[b * 2 + 1], negsum);
        __threadfence();
        if (atomicAdd(done, 1) == NB - 1) {
            volatile const float* va = accB;
            volatile const int* vn = npos;
            int n = 0;
            float a0 = 0.f, a1 = 0.f;
            for (int bb = 0; bb < NB; ++bb) {
                n += vn[bb];
                a0 += va[bb * 2 + 0];
                a1 += va[bb * 2 + 1];
            }
            const float N = (float)n;
            out[0] = a0 / N;
            out[1] = a1 / N;
        }
    }
}

// ---------------------------------------------------------------- select PROBE
// DIAGNOSTIC x16 on real lrk into dummy accB2: s = dur/16.
__global__ __launch_bounds__(1024) void k_select_probe(
    const float* __restrict__ lrk, const int* __restrict__ npos,
    float* __restrict__ accB2) {
    const int b = blockIdx.x;
    const float4* row4 = (const float4*)(lrk + (size_t)b * NP);
    const int tid = threadIdx.x;
    const int lane = tid & 63;
    const int wid = tid >> 6;
    const int sub = lane & 15;

    __shared__ unsigned hist16[2048][16];
    __shared__ unsigned chist[2048];
    __shared__ int sh_bucket, sh_knew;
    __shared__ float wsum[16];
    __shared__ int wcnt[16];

    float4 cch[7];
    bool cvz[7];
#pragma unroll
    for (int j = 0; j < 7; ++j) {
        const int i = tid + j * 1024;
        cvz[j] = (i < NP / 4);
        cch[j] = cvz[j] ? row4[i] : make_float4(0.f, 0.f, 0.f, 0.f);
    }
    const int K0 = min(npos[b] * NEGPOS_I, NP);
    for (int rep = 0; rep < 16; ++rep) {
        const float negsum = select_body(cch, cvz, K0, tid, lane, wid, sub,
                                         hist16, chist, &sh_bucket, &sh_knew,
                                         wsum, wcnt);
        if (tid == 0) atomicAdd(&accB2[b * 2 + 1], negsum);
        __syncthreads();
    }
}

extern "C" void kernel_launch(void* const* d_in, const int* in_sizes, int n_in,
                              void* d_out, int out_size, void* d_ws, size_t ws_size,
                              hipStream_t stream) {
    const float* pred   = (const float*)d_in[0];
    const float* tboxes = (const float*)d_in[1];
    const int*   tlabels = (const int*)d_in[2];
    const float* priors = (const float*)d_in[3];
    float* out = (float*)d_out;

    char* w = (char*)d_ws;
    float*  lrk = (float*)(w + 8ull * BPCNT);
    u64*    mcand = (u64*)(w + 12ull * BPCNT);
    char*   w2 = w + 12ull * BPCNT + 8ull * NB * NO * MBLK2;
    int*    npos = (int*)w2;
    float*  accB = (float*)(w2 + 4ull * NB);
    int*    done = (int*)(w2 + 4ull * NB + 8ull * NB);
    // diagnostic dummies
    char*   wd = w + (64ull << 20);
    u64*    mcand2 = (u64*)wd;
    float*  accB2 = (float*)(wd + 8ull * NB * NO * MBLK2);

    k_match<<<dim3(MBLK2, NB), dim3(256), 0, stream>>>(
        tboxes, priors, mcand, npos, accB, done);
    k_main<<<dim3(SPB2, NB), dim3(64), 0, stream>>>(
        pred, tboxes, tlabels, priors, mcand, lrk, npos, accB);
    // PROBES on current kernels: m = dur(match_probe)/24, s = dur(select_probe)/16
    k_match_probe<<<dim3(MBLK2, NB), dim3(256), 0, stream>>>(
        tboxes, priors, mcand2);
    k_select_probe<<<dim3(NB), dim3(1024), 0, stream>>>(lrk, npos, accB2);
    k_select<<<dim3(NB), dim3(1024), 0, stream>>>(lrk, npos, accB, done, out);
}

// Round 22
// 105.018 us; speedup vs baseline: 6.4906x; 6.4906x over previous
//
#include <hip/hip_runtime.h>
#include <math.h>

#define NB 32
#define NP 24656
#define NO 16
#define NC 81
#define ND 85   // 4 + NC
#define THRESH_F 0.5f
#define NEGPOS_I 3
#define VAR0_F 0.1f
#define VAR1_F 0.2f
#define NEG_HUGE -1e30f

#define BPCNT (NB * NP)
#define CHB32 771        // 32-row chunks per batch row = ceil(NP/32)
#define SPB2 56          // k_main blocks per batch row
#define CB32 11264       // staged bytes per chunk = 11 x 1024

typedef unsigned long long u64;

// ---------------------------------------------------------------- stage (reg)
__device__ __forceinline__ void stage_load(float4* vreg,
                                           const char* __restrict__ gpred,
                                           int b, int r0, int lane) {
    const size_t off = ((size_t)b * NP + r0) * 340ull;
    const char* g = gpred + off;
    const bool unsafe = (b == NB - 1) && (r0 + 34 > NP);
    if (!unsafe) {
#pragma unroll
        for (int k = 0; k < 11; ++k)
            vreg[k] = *(const float4*)(g + k * 1024 + lane * 16);
    } else {
        const int nf4 = (NP - r0) * ND / 4;
        const float4* gs = (const float4*)g;
#pragma unroll
        for (int k = 0; k < 11; ++k) {
            const int idx = k * 64 + lane;
            vreg[k] = (idx < nf4) ? gs[idx]
                                  : make_float4(0.f, 0.f, 0.f, 0.f);
        }
    }
}

__device__ __forceinline__ void stage_write(char* buf, const float4* vreg,
                                            int lane) {
#pragma unroll
    for (int k = 0; k < 11; ++k)
        *(float4*)(buf + k * 1024 + lane * 16) = vreg[k];
}

__device__ __forceinline__ float sl1enc(const float l0, const float l1,
                                        const float l2, const float l3,
                                        const float4 pq,
                                        const float* __restrict__ tb4) {
    const float tx0 = tb4[0], ty0 = tb4[1], tx1 = tb4[2], ty1 = tb4[3];
    const float g0 = ((tx0 + tx1) * 0.5f - pq.x) / (VAR0_F * pq.z);
    const float g1 = ((ty0 + ty1) * 0.5f - pq.y) / (VAR0_F * pq.w);
    const float g2 = __logf((tx1 - tx0) / pq.z) / VAR1_F;
    const float g3 = __logf((ty1 - ty0) / pq.w) / VAR1_F;
    float s = 0.f, dd, ad;
    dd = l0 - g0; ad = fabsf(dd); s += (ad < 1.f) ? 0.5f * dd * dd : (ad - 0.5f);
    dd = l1 - g1; ad = fabsf(dd); s += (ad < 1.f) ? 0.5f * dd * dd : (ad - 0.5f);
    dd = l2 - g2; ad = fabsf(dd); s += (ad < 1.f) ? 0.5f * dd * dd : (ad - 0.5f);
    dd = l3 - g3; ad = fabsf(dd); s += (ad < 1.f) ? 0.5f * dd * dd : (ad - 0.5f);
    return s;
}

// ---------------------------------------------------------------- main fused
// R22: k_match DELETED. Main computes UNFORCED pos/neg; per-o argmax keys
// accumulated as a byproduct of the (already-computed) fused-IoU loop
// (8 u64 max/chunk/lane). Per-block partials via plain stores (no atomics,
// no init). Forced-positive corrections applied later in k_select.
__global__ __launch_bounds__(64) void k_main(
    const float* __restrict__ pred, const float* __restrict__ tboxes,
    const int* __restrict__ tlabels, const float* __restrict__ priors,
    float* __restrict__ lr, u64* __restrict__ bcand,
    float* __restrict__ pll, float* __restrict__ pce,
    float* __restrict__ pnp) {
    __shared__ char smem[2][CB32];
    __shared__ float tbs[NO * 4];
    __shared__ u64 kk[16][32];
    __shared__ u64 pb2[16][4];

    const int b = blockIdx.y;
    const int span = blockIdx.x;
    const int lane = threadIdx.x;
    const size_t bbase = (size_t)b * NP;
    const char* gpred = (const char*)pred;

    char* cur = smem[0];
    char* nxt = smem[1];

    const int rho = lane >> 1;
    const int h = lane & 1;
    const int c0 = rho & 3;
    const int Ab = 16 * (21 * rho + (rho >> 2));
    const int sbase = h ? 11 : 1;

    tbs[lane] = tboxes[b * NO * 4 + lane];

    u64 ok[8];
#pragma unroll
    for (int j = 0; j < 8; ++j) ok[j] = 0ull;

    float my_ll = 0.f, my_ce = 0.f;
    int my_np = 0;

    int chunk = span;
    int next_chunk = chunk + SPB2;
    {
        float4 vreg[11];
        stage_load(vreg, gpred, b, chunk * 32, lane);
        stage_write(cur, vreg, lane);
    }

    while (chunk < CHB32) {
        float4 vreg[11];
        const bool have_next = (next_chunk < CHB32);
        if (have_next)
            stage_load(vreg, gpred, b, next_chunk * 32, lane);

        const int r0 = chunk * 32;
        const int nrows = min(32, NP - r0);
        const int p = r0 + rho;
        const bool rok = (rho < nrows);

        float4 v[11];
#pragma unroll
        for (int k = 0; k < 11; ++k)
            v[k] = *(const float4*)(cur + Ab + 16 * (sbase + k));

        float vals[44];
#pragma unroll
        for (int k = 0; k < 11; ++k) {
            const float xs[4] = {v[k].x, v[k].y, v[k].z, v[k].w};
#pragma unroll
            for (int t = 0; t < 4; ++t) {
                bool okv;
                if (k == 0)
                    okv = h ? false : (t >= c0);
                else if (k == 10)
                    okv = h ? (t <= c0) : true;
                else
                    okv = true;
                vals[4 * k + t] = okv ? xs[t] : NEG_HUGE;
            }
        }
        float mA = vals[0], mB = vals[1];
#pragma unroll
        for (int j = 2; j < 44; j += 2) {
            mA = fmaxf(mA, vals[j]);
            mB = fmaxf(mB, vals[j + 1]);
        }
        float m = fmaxf(mA, mB);
        m = fmaxf(m, __shfl_xor(m, 1, 64));

        float sA = 0.f, sB = 0.f;
#pragma unroll
        for (int j = 0; j < 44; j += 2) {
            sA += __expf(vals[j] - m);
            sB += __expf(vals[j + 1] - m);
        }
        float ssum = sA + sB;
        ssum += __shfl_xor(ssum, 1, 64);
        const float lse = m + __logf(ssum);

        // fused IoU loop: row decision + per-o argmax byproduct
        float bv = -1.f;
        int bi = 0;
        {
            const float4 pq = rok ? *((const float4*)priors + p)
                                  : make_float4(0.f, 0.f, 1.f, 1.f);
            const float prl = pq.x - pq.z * 0.5f, prt = pq.y - pq.w * 0.5f;
            const float prr2 = pq.x + pq.z * 0.5f, prb = pq.y + pq.w * 0.5f;
            const float parea = (prr2 - prl) * (prb - prt);
            const int obase = h * 8;
#pragma unroll
            for (int oj = 0; oj < 8; ++oj) {
                const int o = obase + oj;
                const float al = tbs[o * 4 + 0], at = tbs[o * 4 + 1];
                const float ar = tbs[o * 4 + 2], ab = tbs[o * 4 + 3];
                float iw = fminf(ar, prr2) - fmaxf(al, prl); iw = fmaxf(iw, 0.f);
                float ih = fminf(ab, prb) - fmaxf(at, prt); ih = fmaxf(ih, 0.f);
                const float inter = iw * ih;
                const float aarea = (ar - al) * (ab - at);
                const float iou = inter / (aarea + parea - inter);
                if (iou > bv) { bv = iou; bi = o; }
                if (rok) {
                    const u64 key = ((u64)__float_as_uint(iou) << 32) |
                                    (u64)(0xFFFFFFFFu - (unsigned)p);
                    ok[oj] = (key > ok[oj]) ? key : ok[oj];
                }
            }
            const float ov = __shfl_xor(bv, 1, 64);
            const int oi = __shfl_xor(bi, 1, 64);
            if (ov > bv || (ov == bv && oi < bi)) { bv = ov; bi = oi; }
        }

        if (h == 0 && rok) {
            const float bg = (c0 == 0) ? v[0].x : (c0 == 1) ? v[0].y
                           : (c0 == 2) ? v[0].z : v[0].w;
            const bool pos = (bv >= THRESH_F);     // UNFORCED
            const int o = bi;
            lr[bbase + p] = pos ? 0.f : (lse - bg);
            if (pos) {
                my_np += 1;
                const float* rowp = (const float*)(cur + 340 * rho);
                const int lbl = tlabels[b * NO + o] + 1;
                my_ce += lse - rowp[4 + lbl];
                const float4 pq = *((const float4*)priors + p);
                my_ll += sl1enc(rowp[0], rowp[1], rowp[2], rowp[3], pq,
                                &tbs[o * 4]);
            }
        }

        if (have_next)
            stage_write(nxt, vreg, lane);

        chunk = next_chunk;
        next_chunk += SPB2;
        char* tmp = cur; cur = nxt; nxt = tmp;
    }

    // per-block partial reduce (plain stores -> no init/atomics needed)
    for (int d2 = 1; d2 < 64; d2 <<= 1) {
        my_ll += __shfl_xor(my_ll, d2, 64);
        my_ce += __shfl_xor(my_ce, d2, 64);
        my_np += __shfl_xor(my_np, d2, 64);
    }
    if (lane == 0) {
        pll[b * SPB2 + span] = my_ll;
        pce[b * SPB2 + span] = my_ce;
        pnp[b * SPB2 + span] = (float)my_np;
    }

    // per-o block candidate reduce: kk[16][32] -> pb2[16][4] -> bcand
#pragma unroll
    for (int j = 0; j < 8; ++j) kk[h * 8 + j][rho] = ok[j];
    __syncthreads();
    {
        const int o = lane >> 2, seg = lane & 3;
        u64 m2 = 0ull;
#pragma unroll
        for (int i = 0; i < 8; ++i) {
            const u64 vv = kk[o][seg * 8 + i];
            m2 = (vv > m2) ? vv : m2;
        }
        pb2[o][seg] = m2;
    }
    __syncthreads();
    if (lane < NO) {
        u64 m2 = pb2[lane][0];
#pragma unroll
        for (int i = 1; i < 4; ++i) {
            const u64 vv = pb2[lane][i];
            m2 = (vv > m2) ? vv : m2;
        }
        bcand[((size_t)b * NO + lane) * SPB2 + span] = m2;
    }
}

// ---------------------------------------------------------------- select
// R22: prologue reduces bcand -> forced rows (<=16/b), applies Delta-
// corrections (quad lse recompute) and zeroes lrk at forced-unforced-neg
// rows BEFORE the register-cache load; then the 3-pass radix as before.
__global__ __launch_bounds__(1024) void k_select(
    const float* __restrict__ pred, const float* __restrict__ tboxes,
    const int* __restrict__ tlabels, const float* __restrict__ priors,
    float* __restrict__ lrk, const u64* __restrict__ bcand,
    const float* __restrict__ pll, const float* __restrict__ pce,
    const float* __restrict__ pnp, float* __restrict__ pout) {
    const int b = blockIdx.x;
    const int tid = threadIdx.x;
    const int lane = tid & 63;
    const int wid = tid >> 6;
    const int sub = lane & 15;

    __shared__ unsigned hist16[2048][16];  // 128 KiB
    __shared__ unsigned chist[2048];
    __shared__ int sh_bucket, sh_knew;
    __shared__ float wsum[16];
    __shared__ int wcnt[16];
    __shared__ float tbs[NO * 4];
    __shared__ int tl[NO];
    __shared__ u64 pbq[16][4];
    __shared__ int p16s[16];
    __shared__ float sparts[56 * 3];
    __shared__ float sll, sce, snp_f;
    __shared__ float fll, fce;
    __shared__ int fnp;

    // phase A: loads + candidate partial reduce + partial-sum staging
    if (tid < NO * 4) tbs[tid] = tboxes[b * NO * 4 + tid];
    if (tid >= 128 && tid < 128 + NO) tl[tid - 128] = tlabels[b * NO + tid - 128];
    if (tid < 64) {
        const int o = tid & 15, grp = tid >> 4;
        const u64* c = bcand + ((size_t)b * NO + o) * SPB2 + grp * 14;
        u64 m = 0ull;
        for (int i = 0; i < 14; ++i) {
            const u64 v = c[i];
            m = (v > m) ? v : m;
        }
        pbq[o][grp] = m;
    }
    if (tid >= 64 && tid < 120) {
        const int l = tid - 64;
        sparts[l * 3 + 0] = pll[b * SPB2 + l];
        sparts[l * 3 + 1] = pce[b * SPB2 + l];
        sparts[l * 3 + 2] = pnp[b * SPB2 + l];
    }
    __syncthreads();
    // phase B: finalize p16s + serial partial sums
    if (tid < NO) {
        u64 m = pbq[tid][0];
#pragma unroll
        for (int i = 1; i < 4; ++i) {
            const u64 v = pbq[tid][i];
            m = (v > m) ? v : m;
        }
        p16s[tid] = (int)(0xFFFFFFFFu - (unsigned)(m & 0xFFFFFFFFull));
    }
    if (tid == 32) {
        float a = 0.f, c = 0.f, n = 0.f;
        for (int l = 0; l < 56; ++l) {
            a += sparts[l * 3 + 0];
            c += sparts[l * 3 + 1];
            n += sparts[l * 3 + 2];
        }
        sll = a; sce = c; snp_f = n;
    }
    __syncthreads();
    // phase C: fixup (wave 0; 4 lanes per forced slot)
    if (tid < 64) {
        const int g = lane >> 2, q = lane & 3;
        const int p = p16s[g];
        bool winner = true;
        for (int o2 = g + 1; o2 < NO; ++o2)
            if (p16s[o2] == p) winner = false;
        float dll = 0.f, dce = 0.f;
        int dnp = 0;
        if (winner) {
            const float* base = pred + (size_t)b * NP * ND;
            const int A = 21 * p + (p >> 2), c0 = p & 3;
            const float4* vp = (const float4*)base + A;
            // quad masked lse (R6-verified masking)
            float vals[24];
#pragma unroll
            for (int k = 0; k < 6; ++k) {
                const int s = q + 4 * k;
                const float4 f4 = vp[(s <= 21) ? s : 21];
                const float xs[4] = {f4.x, f4.y, f4.z, f4.w};
#pragma unroll
                for (int t = 0; t < 4; ++t) {
                    const int d = 4 * s + t - c0;
                    vals[4 * k + t] =
                        (s <= 21 && d >= 4 && d <= 84) ? xs[t] : NEG_HUGE;
                }
            }
            float mx = vals[0];
#pragma unroll
            for (int j = 1; j < 24; ++j) mx = fmaxf(mx, vals[j]);
            mx = fmaxf(mx, __shfl_xor(mx, 1, 64));
            mx = fmaxf(mx, __shfl_xor(mx, 2, 64));
            float es = 0.f;
#pragma unroll
            for (int j = 0; j < 24; ++j) es += __expf(vals[j] - mx);
            es += __shfl_xor(es, 1, 64);
            es += __shfl_xor(es, 2, 64);
            const float lse = mx + __logf(es);
            // unforced best-truth for row p (4 o's per lane)
            const float4 pq = *((const float4*)priors + p);
            const float prl = pq.x - pq.z * 0.5f, prt = pq.y - pq.w * 0.5f;
            const float prr2 = pq.x + pq.z * 0.5f, prb = pq.y + pq.w * 0.5f;
            const float parea = (prr2 - prl) * (prb - prt);
            float bv = -1.f;
            int bi = 0;
#pragma unroll
            for (int jj = 0; jj < 4; ++jj) {
                const int o2 = q * 4 + jj;
                const float al = tbs[o2 * 4 + 0], at = tbs[o2 * 4 + 1];
                const float ar = tbs[o2 * 4 + 2], ab = tbs[o2 * 4 + 3];
                float iw = fminf(ar, prr2) - fmaxf(al, prl); iw = fmaxf(iw, 0.f);
                float ih = fminf(ab, prb) - fmaxf(at, prt); ih = fmaxf(ih, 0.f);
                const float inter = iw * ih;
                const float aarea = (ar - al) * (ab - at);
                const float iou = inter / (aarea + parea - inter);
                if (iou > bv) { bv = iou; bi = o2; }
            }
#pragma unroll
            for (int d = 1; d <= 2; d <<= 1) {
                const float ov = __shfl_xor(bv, d, 64);
                const int oi = __shfl_xor(bi, d, 64);
                if (ov > bv || (ov == bv && oi < bi)) { bv = ov; bi = oi; }
            }
            if (q == 0) {
                const float* rowp = base + (size_t)p * ND;
                const float l0 = rowp[0], l1 = rowp[1];
                const float l2 = rowp[2], l3 = rowp[3];
                const bool was_pos = (bv >= THRESH_F);
                const float ce_f = lse - rowp[4 + tl[g] + 1];
                const float ll_f = sl1enc(l0, l1, l2, l3, pq, &tbs[g * 4]);
                if (was_pos) {
                    const float ce_nf = lse - rowp[4 + tl[bi] + 1];
                    const float ll_nf = sl1enc(l0, l1, l2, l3, pq, &tbs[bi * 4]);
                    dll = ll_f - ll_nf;
                    dce = ce_f - ce_nf;
                } else {
                    dll = ll_f;
                    dce = ce_f;
                    dnp = 1;
                    lrk[(size_t)b * NP + p] = 0.f;   // forced row leaves neg set
                }
            }
        }
        for (int d2 = 1; d2 < 64; d2 <<= 1) {
            dll += __shfl_xor(dll, d2, 64);
            dce += __shfl_xor(dce, d2, 64);
            dnp += __shfl_xor(dnp, d2, 64);
        }
        if (lane == 0) { fll = dll; fce = dce; fnp = dnp; }
    }
    __threadfence_block();
    __syncthreads();

    const float llb = sll + fll;
    const float ceb = sce + fce;
    const int npb = (int)(snp_f + 0.5f) + fnp;

    // phase D: register-cache + 3-pass radix (post-fix lrk)
    const float4* row4 = (const float4*)(lrk + (size_t)b * NP);
    float4 cch[7];
    bool cvz[7];
#pragma unroll
    for (int j = 0; j < 7; ++j) {
        const int i = tid + j * 1024;
        cvz[j] = (i < NP / 4);
        cch[j] = cvz[j] ? row4[i] : make_float4(0.f, 0.f, 0.f, 0.f);
    }

    const int K0 = min(npb * NEGPOS_I, NP);
    int k = K0;
    unsigned prefix = 0;
    const int shifts[3] = {21, 10, 0};
    const unsigned masks[3] = {0u, 0xFFE00000u, 0xFFFFFC00u};

    for (int pass = 0; pass < 3; ++pass) {
        const int shift = shifts[pass];
        const unsigned mask_hi = masks[pass];
        {
            uint4* hz = (uint4*)hist16;
            for (int j = tid; j < 2048 * 4; j += 1024)
                hz[j] = make_uint4(0u, 0u, 0u, 0u);
        }
        __syncthreads();
#pragma unroll
        for (int j = 0; j < 7; ++j) {
            if (cvz[j]) {
                const float4 v4 = cch[j];
#pragma unroll
                for (int c = 0; c < 4; ++c) {
                    const float f = (c == 0) ? v4.x : (c == 1) ? v4.y
                                  : (c == 2) ? v4.z : v4.w;
                    const unsigned v = __float_as_uint(f);
                    if ((v & mask_hi) == (prefix & mask_hi))
                        atomicAdd(&hist16[(v >> shift) & 2047u][sub], 1u);
                }
            }
        }
        __syncthreads();
        for (int j = tid; j < 2048; j += 1024) {
            const uint4* hp = (const uint4*)&hist16[j][0];
            const uint4 a = hp[0], b4 = hp[1], c4 = hp[2], d4 = hp[3];
            chist[j] = a.x + a.y + a.z + a.w + b4.x + b4.y + b4.z + b4.w +
                       c4.x + c4.y + c4.z + c4.w + d4.x + d4.y + d4.z + d4.w;
        }
        __syncthreads();
        if (tid < 64) {
            unsigned g = 0;
            for (int j = 0; j < 32; ++j) g += chist[lane * 32 + j];
            unsigned T = g;
            for (int d = 1; d < 64; d <<= 1) {
                const unsigned t = __shfl_down(T, d, 64);
                if (lane + d < 64) T += t;
            }
            const unsigned E = T - g;
            const bool hit = (E < (unsigned)k) && ((unsigned)k <= T);
            const unsigned long long msk = __ballot(hit);
            const int wl = __ffsll(msk) - 1;
            if (lane == wl) {
                unsigned cum = E;
                int bsel = lane * 32, kn = k;
                for (int j = 31; j >= 0; --j) {
                    const unsigned c = chist[lane * 32 + j];
                    if (cum + c >= (unsigned)k) {
                        bsel = lane * 32 + j;
                        kn = k - (int)cum;
                        break;
                    }
                    cum += c;
                }
                sh_bucket = bsel;
                sh_knew = kn;
            }
        }
        __syncthreads();
        prefix |= ((unsigned)sh_bucket) << shift;
        k = sh_knew;
        __syncthreads();
    }
    const float T = __uint_as_float(prefix);

    float msum = 0.f;
    int mcnt = 0;
#pragma unroll
    for (int j = 0; j < 7; ++j) {
        if (cvz[j]) {
            const float4 v4 = cch[j];
#pragma unroll
            for (int c = 0; c < 4; ++c) {
                const float f = (c == 0) ? v4.x : (c == 1) ? v4.y
                              : (c == 2) ? v4.z : v4.w;
                if (__float_as_uint(f) > prefix) { msum += f; mcnt++; }
            }
        }
    }
    for (int s = 32; s > 0; s >>= 1) {
        msum += __shfl_down(msum, s, 64);
        mcnt += __shfl_down(mcnt, s, 64);
    }
    if (lane == 0) { wsum[wid] = msum; wcnt[wid] = mcnt; }
    __syncthreads();
    if (tid == 0) {
        float tot = 0.f;
        int cnt = 0;
        for (int w = 0; w < 16; ++w) { tot += wsum[w]; cnt += wcnt[w]; }
        const float negsum = tot + (float)(K0 - cnt) * T;
        pout[b * 4 + 0] = llb;
        pout[b * 4 + 1] = ceb + negsum;
        pout[b * 4 + 2] = (float)npb;
    }
}

// ---------------------------------------------------------------- final
__global__ void k_final(const float* __restrict__ pout,
                        float* __restrict__ out) {
    if (threadIdx.x == 0 && blockIdx.x == 0) {
        float a0 = 0.f, a1 = 0.f, n = 0.f;
        for (int b = 0; b < NB; ++b) {
            a0 += pout[b * 4 + 0];
            a1 += pout[b * 4 + 1];
            n += pout[b * 4 + 2];
        }
        out[0] = a0 / n;
        out[1] = a1 / n;
    }
}

extern "C" void kernel_launch(void* const* d_in, const int* in_sizes, int n_in,
                              void* d_out, int out_size, void* d_ws, size_t ws_size,
                              hipStream_t stream) {
    const float* pred   = (const float*)d_in[0];
    const float* tboxes = (const float*)d_in[1];
    const int*   tlabels = (const int*)d_in[2];
    const float* priors = (const float*)d_in[3];
    float* out = (float*)d_out;

    char* w = (char*)d_ws;
    float* lrk  = (float*)w;                                  // 4*BPCNT
    u64*   bcand = (u64*)(w + 4ull * BPCNT);                  // NB*NO*SPB2 u64
    char*  w2 = w + 4ull * BPCNT + 8ull * NB * NO * SPB2;
    float* pll = (float*)w2;                                  // NB*SPB2
    float* pce = (float*)(w2 + 4ull * NB * SPB2);
    float* pnp = (float*)(w2 + 8ull * NB * SPB2);
    float* pout = (float*)(w2 + 12ull * NB * SPB2);           // NB*4

    k_main<<<dim3(SPB2, NB), dim3(64), 0, stream>>>(
        pred, tboxes, tlabels, priors, lrk, bcand, pll, pce, pnp);
    k_select<<<dim3(NB), dim3(1024), 0, stream>>>(
        pred, tboxes, tlabels, priors, lrk, bcand, pll, pce, pnp, pout);
    k_final<<<dim3(1), dim3(1), 0, stream>>>(pout, out);
}